// Round 15
// baseline (1255.092 us; speedup 1.0000x reference)
//
#include <hip/hip_runtime.h>
#include <math.h>

// AddrNet eval forward: B=524288, D_MODEL=128, HID=16, N_BINS=256, DEPTH=8.
// Round 15: MFMA-screened argmax with certified exact resolution.
//   - h-trajectory (input layer, embed add, MLP, np-Cephes exp, mul-silu):
//     bit-exact no-FMA R4 contract, unchanged.
//   - logits: bf16 2-term split (h=hi+lo, W=whi+wlo), 2x mfma_f32_16x16x32_bf16
//     per 16x16 tile with swapped-B to keep both cross terms; all bf16
//     products exact in f32; |S - E| <= ~8.5e-5*hmax.
//   - certification: EPS2 = 6e-4*hmax + 1e-5 (3.5x safety).
//     cnt(S_j >= S_max-EPS2): ==1 -> screen idx provably correct;
//     ==2 -> exact no-FMA 2-bin duel (first-index ties);
//     >=3 -> full exact no-FMA 256-bin loop (R4 semantics).

constexpr int BATCH  = 524288;
constexpr int DM     = 128;
constexpr int H      = 16;
constexpr int NB     = 256;
constexpr int DEPTHN = 8;

constexpr int BLOCK = 256;

typedef float v2f    __attribute__((ext_vector_type(2)));
typedef float f32x4  __attribute__((ext_vector_type(4)));
typedef int   i32x4  __attribute__((ext_vector_type(4)));
typedef short bf16x8 __attribute__((ext_vector_type(8)));

__device__ __forceinline__ unsigned bf16_rne(float f) {
    unsigned u = __builtin_bit_cast(unsigned, f);
    return (u + 0x7fffu + ((u >> 16) & 1u)) >> 16;   // RNE, no NaN expected
}
__device__ __forceinline__ float bf16_to_f(unsigned b) {
    return __builtin_bit_cast(float, b << 16);
}

__device__ __forceinline__ float np_expf(float x) {
    // numpy SIMD f32 exp replica (Cephes). Part of the verified R4 contract.
    const float LOG2E = 1.442695040888963407f;
    const float C1    = 0.693359375f;
    const float C2    = -2.12194440e-4f;
    float q = rintf(x * LOG2E);
    float r = __builtin_fmaf(q, -C1, x);
    r = __builtin_fmaf(q, -C2, r);
    float p = 1.9875691500E-4f;
    p = __builtin_fmaf(p, r, 1.3981999507E-3f);
    p = __builtin_fmaf(p, r, 8.3334519073E-3f);
    p = __builtin_fmaf(p, r, 4.1665795894E-2f);
    p = __builtin_fmaf(p, r, 1.6666665459E-1f);
    p = __builtin_fmaf(p, r, 5.0000001201E-1f);
    p = __builtin_fmaf(p, r * r, r);
    p = p + 1.0f;
    if (x > 88.72283935546875f)      return INFINITY;
    if (x < -103.97208404541015625f) return 0.0f;
    return ldexpf(p, (int)q);
}

// ---- prep (same as R11/R14): exact-path weight layouts in d_ws.
//   ws[p*32 + k*2 + hh] = W_out[k][2p+hh]   p in [0,128)
//   ws[4096 + i*16 + k] = W_mlp[k][i]
__global__ void addrnet_prep_kernel(const float* __restrict__ W_out,
                                    const float* __restrict__ W_mlp,
                                    float* __restrict__ ws) {
    int t = threadIdx.x;
    for (int i = t; i < NB * H; i += 256) {
        int p = i >> 5, r = i & 31;
        int k = r >> 1, hh = r & 1;
        ws[i] = W_out[k * NB + (2 * p + hh)];
    }
    {
        int ii = t >> 4, k = t & 15;
        ws[NB * H + ii * H + k] = W_mlp[k * H + ii];
    }
}

__global__ __launch_bounds__(BLOCK) void addrnet_r15_kernel(
    const float* __restrict__ x,      // [B,128]
    const float* __restrict__ W_in,   // [128,16]
    const float* __restrict__ b_in,   // [16]
    const float* __restrict__ embed,  // [256,16]
    const float* __restrict__ b_mlp,  // [16]
    const float* __restrict__ b_out,  // [256]
    const float* __restrict__ W_out,  // [16,256] (for B-frag build)
    const float* __restrict__ ws,     // exact-path layouts
    int* __restrict__ out)            // [B,8] int32
{
#pragma clang fp contract(off)
    // B-fragments: [coltile c][variant m][lane][4 dwords] = 32 KB
    __shared__ __align__(16) int sB[16][2][64][4];
    // A stage: per wave, 64 rows x 17 dwords (pad -> conflict-free) = 17408 B
    __shared__ int sStage[4][64 * 17];
    // per-wave row results
    __shared__ int sRes[4][64];

    const int tid = threadIdx.x;
    const int ln  = tid & 63;
    const int wid = tid >> 6;

    // ---- build B-fragments: B[k][col], lane l holds k=(l>>4)*8+j, col=l&15.
    //      variant 0: k<16 -> whi_k, k>=16 -> wlo_{k-16}
    //      variant 1: k<16 -> wlo_k, k>=16 -> whi_{k-16}
    for (int slot = tid; slot < 16 * 2 * 64; slot += BLOCK) {
        int c = slot >> 7, m = (slot >> 6) & 1, l = slot & 63;
        int col = c * 16 + (l & 15);
        int k0  = (l >> 4) * 8;
        for (int j = 0; j < 4; ++j) {
            unsigned e2[2];
            for (int e = 0; e < 2; ++e) {
                int k  = k0 + 2 * j + e;
                int kk = (k < 16) ? k : k - 16;
                float w = W_out[kk * NB + col];
                unsigned whi = bf16_rne(w);
                unsigned wlo = bf16_rne(w - bf16_to_f(whi));
                int pick_hi = ((k < 16) ? 1 : 0) ^ m;
                e2[e] = pick_hi ? whi : wlo;
            }
            sB[c][m][l][j] = (int)(e2[0] | (e2[1] << 16));
        }
    }
    __syncthreads();

    // per-lane bias for col = ln&15 of each col-tile (C-layout col=lane&15)
    float bcol[16];
#pragma unroll
    for (int c = 0; c < 16; ++c) bcol[c] = b_out[c * 16 + (ln & 15)];

    const float* WM = ws + NB * H;                       // WmlpT[i][k]
    const v2f*   WP = reinterpret_cast<const v2f*>(ws);  // exact pair layout

    const int row = blockIdx.x * BLOCK + tid;

    // ---- h = x @ W_in + b_in : EXACT no-FMA, k ascending, bias after ----
    float h[H];
#pragma unroll
    for (int j = 0; j < H; ++j) h[j] = 0.0f;
    const float4* xr = reinterpret_cast<const float4*>(x + (size_t)row * DM);
    for (int k4 = 0; k4 < DM / 4; ++k4) {
        float4 v = xr[k4];
        const float* w0 = &W_in[(k4 * 4 + 0) * H];
        const float* w1 = &W_in[(k4 * 4 + 1) * H];
        const float* w2 = &W_in[(k4 * 4 + 2) * H];
        const float* w3 = &W_in[(k4 * 4 + 3) * H];
#pragma unroll
        for (int j = 0; j < H; ++j) {
            float a = h[j];
            a = a + v.x * w0[j];
            a = a + v.y * w1[j];
            a = a + v.z * w2[j];
            a = a + v.w * w3[j];
            h[j] = a;
        }
    }
#pragma unroll
    for (int j = 0; j < H; ++j) h[j] = h[j] + b_in[j];

    int* o = out + (size_t)row * DEPTHN;
    int* st = &sStage[wid][ln * 17];
    const int* stw = &sStage[wid][0];

    for (int d = 0; d < DEPTHN; ++d) {
        float hmax = fabsf(h[0]);
#pragma unroll
        for (int k = 1; k < H; ++k) hmax = fmaxf(hmax, fabsf(h[k]));
        const float EPS2 = 6e-4f * hmax + 1e-5f;

        // ---- bf16 2-term split; pack K=32 vector [hi(16)|lo(16)] ----
        int dw[16];
#pragma unroll
        for (int i = 0; i < 8; ++i) {
            unsigned a = bf16_rne(h[2 * i]);
            unsigned b = bf16_rne(h[2 * i + 1]);
            unsigned la = bf16_rne(h[2 * i]     - bf16_to_f(a));
            unsigned lb = bf16_rne(h[2 * i + 1] - bf16_to_f(b));
            dw[i]     = (int)(a  | (b  << 16));
            dw[8 + i] = (int)(la | (lb << 16));
        }
#pragma unroll
        for (int i = 0; i < 16; ++i) st[i] = dw[i];

        // ---- 4 row-tiles of 16: MFMA screen + per-row certify ----
#pragma unroll
        for (int t = 0; t < 4; ++t) {
            // A-frag: lane l = row (l&15)+16t, dwords (l>>4)*4+{0..3}
            int base = (16 * t + (ln & 15)) * 17 + (ln >> 4) * 4;
            i32x4 ai = {stw[base + 0], stw[base + 1], stw[base + 2], stw[base + 3]};
            bf16x8 afrag = __builtin_bit_cast(bf16x8, ai);

            f32x4 accv[16];
#pragma unroll
            for (int c = 0; c < 16; ++c) {
                i32x4 b0i = *reinterpret_cast<const i32x4*>(&sB[c][0][ln][0]);
                i32x4 b1i = *reinterpret_cast<const i32x4*>(&sB[c][1][ln][0]);
                bf16x8 b0 = __builtin_bit_cast(bf16x8, b0i);
                bf16x8 b1 = __builtin_bit_cast(bf16x8, b1i);
                f32x4 acc = {bcol[c], bcol[c], bcol[c], bcol[c]};
                acc = __builtin_amdgcn_mfma_f32_16x16x32_bf16(afrag, b0, acc, 0, 0, 0);
                acc = __builtin_amdgcn_mfma_f32_16x16x32_bf16(afrag, b1, acc, 0, 0, 0);
                accv[c] = acc;
            }

            int resPack[4];
#pragma unroll
            for (int reg = 0; reg < 4; ++reg) {
                // per-lane max over 16 col-tiles (this lane's col = ln&15)
                float mx = accv[0][reg];
                int   gb = 0 * 16 + (ln & 15);
#pragma unroll
                for (int c = 1; c < 16; ++c) {
                    float v = accv[c][reg];
                    int  bb = c * 16 + (ln & 15);
                    bool cg = v > mx;
                    gb = cg ? bb : gb;
                    mx = cg ? v  : mx;
                }
                // 16-lane group reduce (row r = 16t + 4*(ln>>4) + reg)
#pragma unroll
                for (int s = 1; s < 16; s <<= 1) {
                    float pm = __shfl_xor(mx, s);
                    int   pg = __shfl_xor(gb, s);
                    bool tk = pm > mx;
                    mx = tk ? pm : mx;
                    gb = tk ? pg : gb;
                }
                // candidate count + runner-up capture
                float thr = mx - EPS2;
                int cnt = 0, i2 = -1;
#pragma unroll
                for (int c = 0; c < 16; ++c) {
                    float v = accv[c][reg];
                    int  bb = c * 16 + (ln & 15);
                    bool hit = v >= thr;
                    cnt += hit ? 1 : 0;
                    i2 = (hit && bb != gb) ? bb : i2;
                }
#pragma unroll
                for (int s = 1; s < 16; s <<= 1) {
                    cnt += __shfl_xor(cnt, s);
                    int pi = __shfl_xor(i2, s);
                    i2 = pi > i2 ? pi : i2;
                }
                int cc = cnt > 3 ? 3 : cnt;
                resPack[reg] = (gb & 0xff) | ((i2 + 1) << 8) | (cc << 20);
            }
            if ((ln & 15) < 4) {
                int r = ln & 3;
                int p = (r == 0) ? resPack[0] : (r == 1) ? resPack[1]
                       : (r == 2) ? resPack[2] : resPack[3];
                sRes[wid][16 * t + 4 * (ln >> 4) + r] = p;
            }
        }

        // ---- resolve own row ----
        int packed = sRes[wid][ln];
        int gb  = packed & 0xff;
        int i2  = ((packed >> 8) & 0x1ff) - 1;
        int cnt = (packed >> 20) & 3;

        int bi;
        if (cnt >= 3 || (cnt == 2 && i2 < 0)) {
            // full exact no-FMA argmax (R4 semantics)
            float bb2 = -INFINITY;
            int bj = 0;
            for (int p = 0; p < NB / 2; ++p) {
                const v2f* wr = &WP[p * H];
                float a0 = 0.0f, a1 = 0.0f;
#pragma unroll
                for (int k = 0; k < H; ++k) {
                    v2f w = wr[k];
                    a0 = a0 + h[k] * w.x;
                    a1 = a1 + h[k] * w.y;
                }
                a0 = a0 + b_out[2 * p];
                a1 = a1 + b_out[2 * p + 1];
                if (a0 > bb2) { bb2 = a0; bj = 2 * p; }
                if (a1 > bb2) { bb2 = a1; bj = 2 * p + 1; }
            }
            bi = bj;
        } else if (cnt == 2) {
            // exact 2-bin duel, first-index ties
            int lo = gb < i2 ? gb : i2;
            int hi2 = gb < i2 ? i2 : gb;
            float El = 0.0f, Eh = 0.0f;
            {
                const float* wr = ws + (lo >> 1) * 32 + (lo & 1);
#pragma unroll
                for (int k = 0; k < H; ++k) El = El + h[k] * wr[2 * k];
                El = El + b_out[lo];
            }
            {
                const float* wr = ws + (hi2 >> 1) * 32 + (hi2 & 1);
#pragma unroll
                for (int k = 0; k < H; ++k) Eh = Eh + h[k] * wr[2 * k];
                Eh = Eh + b_out[hi2];
            }
            bi = (Eh > El) ? hi2 : lo;
        } else {
            bi = gb;
        }
        o[d] = bi;

        // ---- h = h + embed[bi] : EXACT (global gather, L1/L2 cached) ----
        {
            const float4* e = reinterpret_cast<const float4*>(embed + bi * H);
#pragma unroll
            for (int q4 = 0; q4 < 4; ++q4) {
                float4 ev = e[q4];
                h[q4 * 4 + 0] = h[q4 * 4 + 0] + ev.x;
                h[q4 * 4 + 1] = h[q4 * 4 + 1] + ev.y;
                h[q4 * 4 + 2] = h[q4 * 4 + 2] + ev.z;
                h[q4 * 4 + 3] = h[q4 * 4 + 3] + ev.w;
            }
        }

        // ---- z = h @ W_mlp + b_mlp ; silu : EXACT no-FMA + np-exp ----
        float hn[H];
#pragma unroll
        for (int i = 0; i < H; ++i) {
            const float* wr = &WM[i * H];
            float acc = 0.0f;
#pragma unroll
            for (int k = 0; k < H; ++k) acc = acc + h[k] * wr[k];
            acc = acc + b_mlp[i];
            float e = np_expf(-acc);
            float s = 1.0f / (1.0f + e);
            hn[i] = acc * s;
        }
#pragma unroll
        for (int i = 0; i < H; ++i) h[i] = hn[i];
    }
}

extern "C" void kernel_launch(void* const* d_in, const int* in_sizes, int n_in,
                              void* d_out, int out_size, void* d_ws, size_t ws_size,
                              hipStream_t stream) {
    const float* x     = (const float*)d_in[0];
    const float* W_in  = (const float*)d_in[1];
    const float* b_in  = (const float*)d_in[2];
    const float* embed = (const float*)d_in[3];
    const float* W_mlp = (const float*)d_in[4];
    const float* b_mlp = (const float*)d_in[5];
    const float* W_out = (const float*)d_in[6];
    const float* b_out = (const float*)d_in[7];
    int* out  = (int*)d_out;
    float* ws = (float*)d_ws;          // needs (4096+256)*4 = 17.4 KB

    addrnet_prep_kernel<<<1, 256, 0, stream>>>(W_out, W_mlp, ws);

    dim3 grid(BATCH / BLOCK);          // 2048 blocks, 8192 waves
    dim3 block(BLOCK);
    addrnet_r15_kernel<<<grid, block, 0, stream>>>(x, W_in, b_in, embed,
                                                   b_mlp, b_out, W_out, ws, out);
}

// Round 16
// 620.039 us; speedup vs baseline: 2.0242x; 2.0242x over previous
//
#include <hip/hip_runtime.h>
#include <math.h>

// AddrNet eval forward: B=524288, D_MODEL=128, HID=16, N_BINS=256, DEPTH=8.
// Round 16: R15's verified MFMA screen + certified exact resolution, with the
// residency fixed:
//  - operand swap: mfma(Wfrag, hfrag, bias) -> C col = batch-row, row = bin.
//    Each lane owns bins of ONE row -> 2-step shfl merge, no sRes staging.
//  - no accv[]: immediate fold into top-3-value/top-2-index running tuples.
//  - W-fragments: single variant in LDS (16 KB); variant1 = read at ln^32.
//  - LDS 37888 (4 blocks/CU), __launch_bounds__(256,2) -> 128 VGPR cap.
// h-trajectory (input, embed, MLP, np-Cephes exp, mul-silu): bit-exact no-FMA
// R4 contract, unchanged. EPS2 certification identical to R15 (absmax-0-valid).

constexpr int BATCH  = 524288;
constexpr int DM     = 128;
constexpr int H      = 16;
constexpr int NB     = 256;
constexpr int DEPTHN = 8;

constexpr int BLOCK = 256;
constexpr int STG   = 20;          // stage stride in dwords (16B-aligned)

typedef float v2f    __attribute__((ext_vector_type(2)));
typedef float f32x4  __attribute__((ext_vector_type(4)));
typedef int   i32x4  __attribute__((ext_vector_type(4)));
typedef short bf16x8 __attribute__((ext_vector_type(8)));

__device__ __forceinline__ unsigned bf16_rne(float f) {
    unsigned u = __builtin_bit_cast(unsigned, f);
    return (u + 0x7fffu + ((u >> 16) & 1u)) >> 16;
}
__device__ __forceinline__ float bf16_to_f(unsigned b) {
    return __builtin_bit_cast(float, b << 16);
}

__device__ __forceinline__ float np_expf(float x) {
    // numpy SIMD f32 exp replica (Cephes). Verified R4 contract — do not touch.
    const float LOG2E = 1.442695040888963407f;
    const float C1    = 0.693359375f;
    const float C2    = -2.12194440e-4f;
    float q = rintf(x * LOG2E);
    float r = __builtin_fmaf(q, -C1, x);
    r = __builtin_fmaf(q, -C2, r);
    float p = 1.9875691500E-4f;
    p = __builtin_fmaf(p, r, 1.3981999507E-3f);
    p = __builtin_fmaf(p, r, 8.3334519073E-3f);
    p = __builtin_fmaf(p, r, 4.1665795894E-2f);
    p = __builtin_fmaf(p, r, 1.6666665459E-1f);
    p = __builtin_fmaf(p, r, 5.0000001201E-1f);
    p = __builtin_fmaf(p, r * r, r);
    p = p + 1.0f;
    if (x > 88.72283935546875f)      return INFINITY;
    if (x < -103.97208404541015625f) return 0.0f;
    return ldexpf(p, (int)q);
}

// ---- prep: exact-path weight layouts in d_ws (same as R14/R15).
//   ws[p*32 + k*2 + hh] = W_out[k][2p+hh]   p in [0,128)
//   ws[4096 + i*16 + k] = W_mlp[k][i]
__global__ void addrnet_prep_kernel(const float* __restrict__ W_out,
                                    const float* __restrict__ W_mlp,
                                    float* __restrict__ ws) {
    int t = threadIdx.x;
    for (int i = t; i < NB * H; i += 256) {
        int p = i >> 5, r = i & 31;
        int k = r >> 1, hh = r & 1;
        ws[i] = W_out[k * NB + (2 * p + hh)];
    }
    {
        int ii = t >> 4, k = t & 15;
        ws[NB * H + ii * H + k] = W_mlp[k * H + ii];
    }
}

__global__ __launch_bounds__(BLOCK, 2) void addrnet_r16_kernel(
    const float* __restrict__ x,      // [B,128]
    const float* __restrict__ W_in,   // [128,16]
    const float* __restrict__ b_in,   // [16]
    const float* __restrict__ embed,  // [256,16]
    const float* __restrict__ b_mlp,  // [16]
    const float* __restrict__ b_out,  // [256]
    const float* __restrict__ W_out,  // [16,256] (A-frag build)
    const float* __restrict__ ws,     // exact-path layouts
    int* __restrict__ out)            // [B,8] int32
{
#pragma clang fp contract(off)
    __shared__ __align__(16) int   sA[16][64][4];       // 16 KB  W-frags (v0)
    __shared__ __align__(16) int   sStage[4][64 * STG]; // 20 KB  h exchange
    __shared__ __align__(16) float sBias[NB];           //  1 KB

    const int tid = threadIdx.x;
    const int ln  = tid & 63;
    const int wid = tid >> 6;

    // ---- build A-fragments (variant0): lane l: bin m=16*bt+(l&15),
    //      k=(l>>4)*8+2j+e; k<16 -> whi_k, k>=16 -> wlo_{k-16}; w=W_out[kk][m]
    for (int slot = tid; slot < 16 * 64; slot += BLOCK) {
        int bt = slot >> 6, l = slot & 63;
        int m  = 16 * bt + (l & 15);
        int k0 = (l >> 4) * 8;
        for (int j = 0; j < 4; ++j) {
            unsigned e2[2];
            for (int e = 0; e < 2; ++e) {
                int k  = k0 + 2 * j + e;
                int kk = k & 15;
                float w = W_out[kk * NB + m];
                unsigned whi = bf16_rne(w);
                unsigned wlo = bf16_rne(w - bf16_to_f(whi));
                e2[e] = (k < 16) ? whi : wlo;
            }
            sA[bt][l][j] = (int)(e2[0] | (e2[1] << 16));
        }
    }
    if (tid < NB) sBias[tid] = b_out[tid];
    __syncthreads();

    const float* WM = ws + NB * H;                       // WmlpT[i][k]
    const v2f*   WP = reinterpret_cast<const v2f*>(ws);  // exact pair layout

    const int row = blockIdx.x * BLOCK + tid;

    // ---- h = x @ W_in + b_in : EXACT no-FMA, k ascending, bias after ----
    float h[H];
#pragma unroll
    for (int j = 0; j < H; ++j) h[j] = 0.0f;
    const float4* xr = reinterpret_cast<const float4*>(x + (size_t)row * DM);
    for (int k4 = 0; k4 < DM / 4; ++k4) {
        float4 v = xr[k4];
        const float* w0 = &W_in[(k4 * 4 + 0) * H];
        const float* w1 = &W_in[(k4 * 4 + 1) * H];
        const float* w2 = &W_in[(k4 * 4 + 2) * H];
        const float* w3 = &W_in[(k4 * 4 + 3) * H];
#pragma unroll
        for (int j = 0; j < H; ++j) {
            float a = h[j];
            a = a + v.x * w0[j];
            a = a + v.y * w1[j];
            a = a + v.z * w2[j];
            a = a + v.w * w3[j];
            h[j] = a;
        }
    }
#pragma unroll
    for (int j = 0; j < H; ++j) h[j] = h[j] + b_in[j];

    int* o = out + (size_t)row * DEPTHN;
    int* stme = &sStage[wid][ln * STG];
    const int binbase = (ln >> 4) * 4;

    for (int d = 0; d < DEPTHN; ++d) {
        float hmax = fabsf(h[0]);
#pragma unroll
        for (int k = 1; k < H; ++k) hmax = fmaxf(hmax, fabsf(h[k]));
        const float EPS2 = 6e-4f * hmax + 1e-5f;

        // ---- bf16 2-term split; dwords [hi pairs(8) | lo pairs(8)] ----
        int dw[16];
#pragma unroll
        for (int i = 0; i < 8; ++i) {
            unsigned a  = bf16_rne(h[2 * i]);
            unsigned b  = bf16_rne(h[2 * i + 1]);
            unsigned la = bf16_rne(h[2 * i]     - bf16_to_f(a));
            unsigned lb = bf16_rne(h[2 * i + 1] - bf16_to_f(b));
            dw[i]     = (int)(a  | (b  << 16));
            dw[8 + i] = (int)(la | (lb << 16));
        }
        {
            i32x4 s0 = {dw[0], dw[1], dw[2], dw[3]};
            i32x4 s1 = {dw[4], dw[5], dw[6], dw[7]};
            i32x4 s2 = {dw[8], dw[9], dw[10], dw[11]};
            i32x4 s3 = {dw[12], dw[13], dw[14], dw[15]};
            *reinterpret_cast<i32x4*>(&stme[0])  = s0;
            *reinterpret_cast<i32x4*>(&stme[4])  = s1;
            *reinterpret_cast<i32x4*>(&stme[8])  = s2;
            *reinterpret_cast<i32x4*>(&stme[12]) = s3;
        }

        // ---- B-frags (h): rowgroup g, lane ln: row (ln&15)+16g, kgrp ln>>4 ----
        bf16x8 bfr[4];
#pragma unroll
        for (int g = 0; g < 4; ++g) {
            const i32x4* p = reinterpret_cast<const i32x4*>(
                &sStage[wid][((ln & 15) + 16 * g) * STG + (ln >> 4) * 4]);
            bfr[g] = __builtin_bit_cast(bf16x8, *p);
        }

        // running tuples per rowgroup
        float mx0 = -INFINITY, sec0 = -INFINITY, t30 = -INFINITY; int gb0 = 0, i20 = 0;
        float mx1 = -INFINITY, sec1 = -INFINITY, t31 = -INFINITY; int gb1 = 0, i21 = 0;
        float mx2 = -INFINITY, sec2 = -INFINITY, t32 = -INFINITY; int gb2 = 0, i22 = 0;
        float mx3 = -INFINITY, sec3 = -INFINITY, t33 = -INFINITY; int gb3 = 0, i23 = 0;

#define INS(MX, GB, SEC, I2, T3, V, BIN)                                   \
        {                                                                  \
            float v_ = (V); int b_ = (BIN);                                \
            bool c1 = v_ > MX, c2 = v_ > SEC, c3 = v_ > T3;                \
            float ns = c1 ? MX : (c2 ? v_ : SEC);                          \
            int   ni = c1 ? GB : (c2 ? b_ : I2);                           \
            T3  = c2 ? SEC : (c3 ? v_ : T3);                               \
            MX  = c1 ? v_ : MX;  GB = c1 ? b_ : GB;                       \
            SEC = ns;  I2 = ni;                                            \
        }

        for (int bt = 0; bt < 16; ++bt) {
            i32x4 a0i = *reinterpret_cast<const i32x4*>(&sA[bt][ln][0]);
            i32x4 a1i = *reinterpret_cast<const i32x4*>(&sA[bt][ln ^ 32][0]);
            bf16x8 a0 = __builtin_bit_cast(bf16x8, a0i);
            bf16x8 a1 = __builtin_bit_cast(bf16x8, a1i);
            f32x4 bias4 = *reinterpret_cast<const f32x4*>(&sBias[16 * bt + binbase]);
            int bin0 = 16 * bt + binbase;
#pragma unroll
            for (int g = 0; g < 4; ++g) {
                f32x4 acc = bias4;
                acc = __builtin_amdgcn_mfma_f32_16x16x32_bf16(a0, bfr[g], acc, 0, 0, 0);
                acc = __builtin_amdgcn_mfma_f32_16x16x32_bf16(a1, bfr[g], acc, 0, 0, 0);
                if (g == 0) {
                    INS(mx0, gb0, sec0, i20, t30, acc[0], bin0 + 0);
                    INS(mx0, gb0, sec0, i20, t30, acc[1], bin0 + 1);
                    INS(mx0, gb0, sec0, i20, t30, acc[2], bin0 + 2);
                    INS(mx0, gb0, sec0, i20, t30, acc[3], bin0 + 3);
                } else if (g == 1) {
                    INS(mx1, gb1, sec1, i21, t31, acc[0], bin0 + 0);
                    INS(mx1, gb1, sec1, i21, t31, acc[1], bin0 + 1);
                    INS(mx1, gb1, sec1, i21, t31, acc[2], bin0 + 2);
                    INS(mx1, gb1, sec1, i21, t31, acc[3], bin0 + 3);
                } else if (g == 2) {
                    INS(mx2, gb2, sec2, i22, t32, acc[0], bin0 + 0);
                    INS(mx2, gb2, sec2, i22, t32, acc[1], bin0 + 1);
                    INS(mx2, gb2, sec2, i22, t32, acc[2], bin0 + 2);
                    INS(mx2, gb2, sec2, i22, t32, acc[3], bin0 + 3);
                } else {
                    INS(mx3, gb3, sec3, i23, t33, acc[0], bin0 + 0);
                    INS(mx3, gb3, sec3, i23, t33, acc[1], bin0 + 1);
                    INS(mx3, gb3, sec3, i23, t33, acc[2], bin0 + 2);
                    INS(mx3, gb3, sec3, i23, t33, acc[3], bin0 + 3);
                }
            }
        }
#undef INS

        // ---- merge 4 bin-holder lanes (xor 16, 32) per rowgroup; keep own ----
        float kmx = -INFINITY, ksec = -INFINITY, kt3 = -INFINITY;
        int kgb = 0, ki2 = 0;
#define MERGE_KEEP(MX, GB, SEC, I2, T3, G)                                 \
        {                                                                  \
            float mx_ = MX, sec_ = SEC, t3_ = T3; int gb_ = GB, i2_ = I2;  \
            _Pragma("unroll")                                              \
            for (int s = 16; s <= 32; s <<= 1) {                           \
                float pmx = __shfl_xor(mx_, s);                            \
                int   pgb = __shfl_xor(gb_, s);                            \
                float pse = __shfl_xor(sec_, s);                           \
                int   pi2 = __shfl_xor(i2_, s);                            \
                float pt3 = __shfl_xor(t3_, s);                            \
                bool t  = pmx > mx_;                                       \
                float nmx = t ? pmx : mx_;  int ngb = t ? pgb : gb_;       \
                float lmx = t ? mx_ : pmx;  int lgb = t ? gb_ : pgb;       \
                float wse = t ? pse : sec_; int wsi = t ? pi2 : i2_;       \
                bool u  = lmx > wse;                                       \
                float nse = u ? lmx : wse;  int ni2 = u ? lgb : wsi;       \
                float c3  = u ? wse : lmx;                                 \
                float lse = t ? sec_ : pse;                                \
                float nt3 = fmaxf(fmaxf(c3, lse), fmaxf(t3_, pt3));        \
                mx_ = nmx; gb_ = ngb; sec_ = nse; i2_ = ni2; t3_ = nt3;    \
            }                                                              \
            bool own = ((ln >> 4) == (G));                                 \
            kmx = own ? mx_ : kmx;   kgb = own ? gb_ : kgb;                \
            ksec = own ? sec_ : ksec; ki2 = own ? i2_ : ki2;               \
            kt3 = own ? t3_ : kt3;                                         \
        }
        MERGE_KEEP(mx0, gb0, sec0, i20, t30, 0)
        MERGE_KEEP(mx1, gb1, sec1, i21, t31, 1)
        MERGE_KEEP(mx2, gb2, sec2, i22, t32, 2)
        MERGE_KEEP(mx3, gb3, sec3, i23, t33, 3)
#undef MERGE_KEEP

        // ---- certified resolution ----
        int bi;
        if (kmx - kt3 <= EPS2) {
            // full exact no-FMA argmax (rare)
            float bb2 = -INFINITY;
            int bj = 0;
            for (int p = 0; p < NB / 2; ++p) {
                const v2f* wr = &WP[p * H];
                float a0 = 0.0f, a1 = 0.0f;
#pragma unroll
                for (int k = 0; k < H; ++k) {
                    v2f w = wr[k];
                    a0 = a0 + h[k] * w.x;
                    a1 = a1 + h[k] * w.y;
                }
                a0 = a0 + b_out[2 * p];
                a1 = a1 + b_out[2 * p + 1];
                if (a0 > bb2) { bb2 = a0; bj = 2 * p; }
                if (a1 > bb2) { bb2 = a1; bj = 2 * p + 1; }
            }
            bi = bj;
        } else if (kmx - ksec <= EPS2) {
            // exact 2-bin duel, first-index ties
            int lo  = kgb < ki2 ? kgb : ki2;
            int hi2 = kgb < ki2 ? ki2 : kgb;
            float El = 0.0f, Eh = 0.0f;
            {
                const float* wr = ws + (lo >> 1) * 32 + (lo & 1);
#pragma unroll
                for (int k = 0; k < H; ++k) El = El + h[k] * wr[2 * k];
                El = El + b_out[lo];
            }
            {
                const float* wr = ws + (hi2 >> 1) * 32 + (hi2 & 1);
#pragma unroll
                for (int k = 0; k < H; ++k) Eh = Eh + h[k] * wr[2 * k];
                Eh = Eh + b_out[hi2];
            }
            bi = (Eh > El) ? hi2 : lo;
        } else {
            bi = kgb;
        }
        o[d] = bi;

        // ---- h = h + embed[bi] : EXACT (global gather, cached) ----
        {
            const float4* e = reinterpret_cast<const float4*>(embed + bi * H);
#pragma unroll
            for (int q4 = 0; q4 < 4; ++q4) {
                float4 ev = e[q4];
                h[q4 * 4 + 0] = h[q4 * 4 + 0] + ev.x;
                h[q4 * 4 + 1] = h[q4 * 4 + 1] + ev.y;
                h[q4 * 4 + 2] = h[q4 * 4 + 2] + ev.z;
                h[q4 * 4 + 3] = h[q4 * 4 + 3] + ev.w;
            }
        }

        // ---- z = h @ W_mlp + b_mlp ; silu : EXACT no-FMA + np-exp ----
        float hn[H];
#pragma unroll
        for (int i = 0; i < H; ++i) {
            const float* wr = &WM[i * H];
            float acc = 0.0f;
#pragma unroll
            for (int k = 0; k < H; ++k) acc = acc + h[k] * wr[k];
            acc = acc + b_mlp[i];
            float e = np_expf(-acc);
            float s = 1.0f / (1.0f + e);
            hn[i] = acc * s;
        }
#pragma unroll
        for (int i = 0; i < H; ++i) h[i] = hn[i];
    }
}

extern "C" void kernel_launch(void* const* d_in, const int* in_sizes, int n_in,
                              void* d_out, int out_size, void* d_ws, size_t ws_size,
                              hipStream_t stream) {
    const float* x     = (const float*)d_in[0];
    const float* W_in  = (const float*)d_in[1];
    const float* b_in  = (const float*)d_in[2];
    const float* embed = (const float*)d_in[3];
    const float* W_mlp = (const float*)d_in[4];
    const float* b_mlp = (const float*)d_in[5];
    const float* W_out = (const float*)d_in[6];
    const float* b_out = (const float*)d_in[7];
    int* out  = (int*)d_out;
    float* ws = (float*)d_ws;          // needs (4096+256)*4 = 17.4 KB

    addrnet_prep_kernel<<<1, 256, 0, stream>>>(W_out, W_mlp, ws);

    dim3 grid(BATCH / BLOCK);          // 2048 blocks, 8192 waves
    dim3 block(BLOCK);
    addrnet_r16_kernel<<<grid, block, 0, stream>>>(x, W_in, b_in, embed,
                                                   b_mlp, b_out, W_out, ws, out);
}

// Round 18
// 618.565 us; speedup vs baseline: 2.0290x; 1.0024x over previous
//
#include <hip/hip_runtime.h>
#include <math.h>

// AddrNet eval forward: B=524288, D_MODEL=128, HID=16, N_BINS=256, DEPTH=8.
// Round 18: R16 (PASSING, 620us) + ONLY the 9-op INS tracker (med3/min
// identities, case-verified) and tree-hmax. R17's failure was a staging
// overlap bug (16 dwords written into STG=15 stride); STG restored to 20.
//   sec' = med3(mx, sec, v); t3' = max(t3, min(sec, v))  [mx>=sec>=t3 inv.]
// Everything else bit-identical to R16: MFMA bf16-2-term screen (verified),
// EPS2 certification, exact no-FMA h-trajectory (R4 contract), np-Cephes exp.

constexpr int BATCH  = 524288;
constexpr int DM     = 128;
constexpr int H      = 16;
constexpr int NB     = 256;
constexpr int DEPTHN = 8;

constexpr int BLOCK = 256;
constexpr int STG   = 20;          // stage stride in dwords (>=16!), 16B-aligned

typedef float v2f    __attribute__((ext_vector_type(2)));
typedef float f32x4  __attribute__((ext_vector_type(4)));
typedef int   i32x4  __attribute__((ext_vector_type(4)));
typedef short bf16x8 __attribute__((ext_vector_type(8)));

__device__ __forceinline__ unsigned bf16_rne(float f) {
    unsigned u = __builtin_bit_cast(unsigned, f);
    return (u + 0x7fffu + ((u >> 16) & 1u)) >> 16;
}
__device__ __forceinline__ float bf16_to_f(unsigned b) {
    return __builtin_bit_cast(float, b << 16);
}

__device__ __forceinline__ float np_expf(float x) {
    // numpy SIMD f32 exp replica (Cephes). Verified R4 contract — do not touch.
    const float LOG2E = 1.442695040888963407f;
    const float C1    = 0.693359375f;
    const float C2    = -2.12194440e-4f;
    float q = rintf(x * LOG2E);
    float r = __builtin_fmaf(q, -C1, x);
    r = __builtin_fmaf(q, -C2, r);
    float p = 1.9875691500E-4f;
    p = __builtin_fmaf(p, r, 1.3981999507E-3f);
    p = __builtin_fmaf(p, r, 8.3334519073E-3f);
    p = __builtin_fmaf(p, r, 4.1665795894E-2f);
    p = __builtin_fmaf(p, r, 1.6666665459E-1f);
    p = __builtin_fmaf(p, r, 5.0000001201E-1f);
    p = __builtin_fmaf(p, r * r, r);
    p = p + 1.0f;
    if (x > 88.72283935546875f)      return INFINITY;
    if (x < -103.97208404541015625f) return 0.0f;
    return ldexpf(p, (int)q);
}

// ---- prep: exact-path weight layouts in d_ws (same as R14-R16).
//   ws[p*32 + k*2 + hh] = W_out[k][2p+hh]   p in [0,128)
//   ws[4096 + i*16 + k] = W_mlp[k][i]
__global__ void addrnet_prep_kernel(const float* __restrict__ W_out,
                                    const float* __restrict__ W_mlp,
                                    float* __restrict__ ws) {
    int t = threadIdx.x;
    for (int i = t; i < NB * H; i += 256) {
        int p = i >> 5, r = i & 31;
        int k = r >> 1, hh = r & 1;
        ws[i] = W_out[k * NB + (2 * p + hh)];
    }
    {
        int ii = t >> 4, k = t & 15;
        ws[NB * H + ii * H + k] = W_mlp[k * H + ii];
    }
}

__global__ __launch_bounds__(BLOCK, 2) void addrnet_r18_kernel(
    const float* __restrict__ x,      // [B,128]
    const float* __restrict__ W_in,   // [128,16]
    const float* __restrict__ b_in,   // [16]
    const float* __restrict__ embed,  // [256,16]
    const float* __restrict__ b_mlp,  // [16]
    const float* __restrict__ b_out,  // [256]
    const float* __restrict__ W_out,  // [16,256] (A-frag build)
    const float* __restrict__ ws,     // exact-path layouts
    int* __restrict__ out)            // [B,8] int32
{
#pragma clang fp contract(off)
    __shared__ __align__(16) int   sA[16][64][4];       // 16 KB  W-frags (v0)
    __shared__ __align__(16) int   sStage[4][64 * STG]; // 20 KB  h exchange
    __shared__ __align__(16) float sBias[NB];           //  1 KB

    const int tid = threadIdx.x;
    const int ln  = tid & 63;
    const int wid = tid >> 6;

    // ---- build A-fragments (variant0): lane l: bin m=16*bt+(l&15),
    //      k=(l>>4)*8+2j+e; k<16 -> whi_k, k>=16 -> wlo_{k-16}; w=W_out[kk][m]
    for (int slot = tid; slot < 16 * 64; slot += BLOCK) {
        int bt = slot >> 6, l = slot & 63;
        int m  = 16 * bt + (l & 15);
        int k0 = (l >> 4) * 8;
        for (int j = 0; j < 4; ++j) {
            unsigned e2[2];
            for (int e = 0; e < 2; ++e) {
                int k  = k0 + 2 * j + e;
                int kk = k & 15;
                float w = W_out[kk * NB + m];
                unsigned whi = bf16_rne(w);
                unsigned wlo = bf16_rne(w - bf16_to_f(whi));
                e2[e] = (k < 16) ? whi : wlo;
            }
            sA[bt][l][j] = (int)(e2[0] | (e2[1] << 16));
        }
    }
    if (tid < NB) sBias[tid] = b_out[tid];
    __syncthreads();

    const float* WM = ws + NB * H;                       // WmlpT[i][k]
    const v2f*   WP = reinterpret_cast<const v2f*>(ws);  // exact pair layout

    const int row = blockIdx.x * BLOCK + tid;

    // ---- h = x @ W_in + b_in : EXACT no-FMA, k ascending, bias after ----
    float h[H];
#pragma unroll
    for (int j = 0; j < H; ++j) h[j] = 0.0f;
    const float4* xr = reinterpret_cast<const float4*>(x + (size_t)row * DM);
    for (int k4 = 0; k4 < DM / 4; ++k4) {
        float4 v = xr[k4];
        const float* w0 = &W_in[(k4 * 4 + 0) * H];
        const float* w1 = &W_in[(k4 * 4 + 1) * H];
        const float* w2 = &W_in[(k4 * 4 + 2) * H];
        const float* w3 = &W_in[(k4 * 4 + 3) * H];
#pragma unroll
        for (int j = 0; j < H; ++j) {
            float a = h[j];
            a = a + v.x * w0[j];
            a = a + v.y * w1[j];
            a = a + v.z * w2[j];
            a = a + v.w * w3[j];
            h[j] = a;
        }
    }
#pragma unroll
    for (int j = 0; j < H; ++j) h[j] = h[j] + b_in[j];

    int* o = out + (size_t)row * DEPTHN;
    int* stme = &sStage[wid][ln * STG];
    const int binbase = (ln >> 4) * 4;

    for (int d = 0; d < DEPTHN; ++d) {
        // hmax (tree -> max3 fusable)
        float m01 = fmaxf(fabsf(h[0]), fabsf(h[1]));
        float m23 = fmaxf(fabsf(h[2]), fabsf(h[3]));
        float m45 = fmaxf(fabsf(h[4]), fabsf(h[5]));
        float m67 = fmaxf(fabsf(h[6]), fabsf(h[7]));
        float m89 = fmaxf(fabsf(h[8]), fabsf(h[9]));
        float mab = fmaxf(fabsf(h[10]), fabsf(h[11]));
        float mcd = fmaxf(fabsf(h[12]), fabsf(h[13]));
        float mef = fmaxf(fabsf(h[14]), fabsf(h[15]));
        float hmax = fmaxf(fmaxf(fmaxf(m01, m23), fmaxf(m45, m67)),
                           fmaxf(fmaxf(m89, mab), fmaxf(mcd, mef)));
        const float EPS2 = 6e-4f * hmax + 1e-5f;

        // ---- bf16 2-term split; dwords [hi pairs(8) | lo pairs(8)] ----
        int dw[16];
#pragma unroll
        for (int i = 0; i < 8; ++i) {
            unsigned a  = bf16_rne(h[2 * i]);
            unsigned b  = bf16_rne(h[2 * i + 1]);
            unsigned la = bf16_rne(h[2 * i]     - bf16_to_f(a));
            unsigned lb = bf16_rne(h[2 * i + 1] - bf16_to_f(b));
            dw[i]     = (int)(a  | (b  << 16));
            dw[8 + i] = (int)(la | (lb << 16));
        }
        {
            i32x4 s0 = {dw[0], dw[1], dw[2], dw[3]};
            i32x4 s1 = {dw[4], dw[5], dw[6], dw[7]};
            i32x4 s2 = {dw[8], dw[9], dw[10], dw[11]};
            i32x4 s3 = {dw[12], dw[13], dw[14], dw[15]};
            *reinterpret_cast<i32x4*>(&stme[0])  = s0;
            *reinterpret_cast<i32x4*>(&stme[4])  = s1;
            *reinterpret_cast<i32x4*>(&stme[8])  = s2;
            *reinterpret_cast<i32x4*>(&stme[12]) = s3;
        }

        // ---- B-frags (h): rowgroup g, lane ln: row (ln&15)+16g, kgrp ln>>4 ----
        bf16x8 bfr[4];
#pragma unroll
        for (int g = 0; g < 4; ++g) {
            const i32x4* p = reinterpret_cast<const i32x4*>(
                &sStage[wid][((ln & 15) + 16 * g) * STG + (ln >> 4) * 4]);
            bfr[g] = __builtin_bit_cast(bf16x8, *p);
        }

        // running tuples per rowgroup
        float mx0 = -INFINITY, sec0 = -INFINITY, t30 = -INFINITY; int gb0 = 0, i20 = 0;
        float mx1 = -INFINITY, sec1 = -INFINITY, t31 = -INFINITY; int gb1 = 0, i21 = 0;
        float mx2 = -INFINITY, sec2 = -INFINITY, t32 = -INFINITY; int gb2 = 0, i22 = 0;
        float mx3 = -INFINITY, sec3 = -INFINITY, t33 = -INFINITY; int gb3 = 0, i23 = 0;

        // 9-op insert (case-verified equivalent to R16's 11-op form):
        //   t3' = max(t3, min(sec, v)); idx updates by cmp;
        //   sec' = med3(mx, sec, v);    mx' = max(mx, v)
#define INS(MX, GB, SEC, I2, T3, V, BIN)                                   \
        {                                                                  \
            float v_ = (V); int b_ = (BIN);                                \
            T3 = fmaxf(T3, fminf(SEC, v_));                                \
            bool c1 = v_ > MX;                                             \
            bool c2 = v_ > SEC;                                            \
            I2 = c1 ? GB : (c2 ? b_ : I2);                                 \
            GB = c1 ? b_ : GB;                                             \
            SEC = __builtin_amdgcn_fmed3f(MX, SEC, v_);                    \
            MX = fmaxf(MX, v_);                                            \
        }

        for (int bt = 0; bt < 16; ++bt) {
            i32x4 a0i = *reinterpret_cast<const i32x4*>(&sA[bt][ln][0]);
            i32x4 a1i = *reinterpret_cast<const i32x4*>(&sA[bt][ln ^ 32][0]);
            bf16x8 a0 = __builtin_bit_cast(bf16x8, a0i);
            bf16x8 a1 = __builtin_bit_cast(bf16x8, a1i);
            f32x4 bias4 = *reinterpret_cast<const f32x4*>(&sBias[16 * bt + binbase]);
            int bin0 = 16 * bt + binbase;
#pragma unroll
            for (int g = 0; g < 4; ++g) {
                f32x4 acc = bias4;
                acc = __builtin_amdgcn_mfma_f32_16x16x32_bf16(a0, bfr[g], acc, 0, 0, 0);
                acc = __builtin_amdgcn_mfma_f32_16x16x32_bf16(a1, bfr[g], acc, 0, 0, 0);
                if (g == 0) {
                    INS(mx0, gb0, sec0, i20, t30, acc[0], bin0 + 0);
                    INS(mx0, gb0, sec0, i20, t30, acc[1], bin0 + 1);
                    INS(mx0, gb0, sec0, i20, t30, acc[2], bin0 + 2);
                    INS(mx0, gb0, sec0, i20, t30, acc[3], bin0 + 3);
                } else if (g == 1) {
                    INS(mx1, gb1, sec1, i21, t31, acc[0], bin0 + 0);
                    INS(mx1, gb1, sec1, i21, t31, acc[1], bin0 + 1);
                    INS(mx1, gb1, sec1, i21, t31, acc[2], bin0 + 2);
                    INS(mx1, gb1, sec1, i21, t31, acc[3], bin0 + 3);
                } else if (g == 2) {
                    INS(mx2, gb2, sec2, i22, t32, acc[0], bin0 + 0);
                    INS(mx2, gb2, sec2, i22, t32, acc[1], bin0 + 1);
                    INS(mx2, gb2, sec2, i22, t32, acc[2], bin0 + 2);
                    INS(mx2, gb2, sec2, i22, t32, acc[3], bin0 + 3);
                } else {
                    INS(mx3, gb3, sec3, i23, t33, acc[0], bin0 + 0);
                    INS(mx3, gb3, sec3, i23, t33, acc[1], bin0 + 1);
                    INS(mx3, gb3, sec3, i23, t33, acc[2], bin0 + 2);
                    INS(mx3, gb3, sec3, i23, t33, acc[3], bin0 + 3);
                }
            }
        }
#undef INS

        // ---- merge 4 bin-holder lanes (xor 16, 32) per rowgroup; keep own ----
        float kmx = -INFINITY, ksec = -INFINITY, kt3 = -INFINITY;
        int kgb = 0, ki2 = 0;
#define MERGE_KEEP(MX, GB, SEC, I2, T3, G)                                 \
        {                                                                  \
            float mx_ = MX, sec_ = SEC, t3_ = T3; int gb_ = GB, i2_ = I2;  \
            _Pragma("unroll")                                              \
            for (int s = 16; s <= 32; s <<= 1) {                           \
                float pmx = __shfl_xor(mx_, s);                            \
                int   pgb = __shfl_xor(gb_, s);                            \
                float pse = __shfl_xor(sec_, s);                           \
                int   pi2 = __shfl_xor(i2_, s);                            \
                float pt3 = __shfl_xor(t3_, s);                            \
                bool t  = pmx > mx_;                                       \
                float nmx = t ? pmx : mx_;  int ngb = t ? pgb : gb_;       \
                float lmx = t ? mx_ : pmx;  int lgb = t ? gb_ : pgb;       \
                float wse = t ? pse : sec_; int wsi = t ? pi2 : i2_;       \
                bool u  = lmx > wse;                                       \
                float nse = u ? lmx : wse;  int ni2 = u ? lgb : wsi;       \
                float c3  = u ? wse : lmx;                                 \
                float lse = t ? sec_ : pse;                                \
                float nt3 = fmaxf(fmaxf(c3, lse), fmaxf(t3_, pt3));        \
                mx_ = nmx; gb_ = ngb; sec_ = nse; i2_ = ni2; t3_ = nt3;    \
            }                                                              \
            bool own = ((ln >> 4) == (G));                                 \
            kmx = own ? mx_ : kmx;   kgb = own ? gb_ : kgb;                \
            ksec = own ? sec_ : ksec; ki2 = own ? i2_ : ki2;               \
            kt3 = own ? t3_ : kt3;                                         \
        }
        MERGE_KEEP(mx0, gb0, sec0, i20, t30, 0)
        MERGE_KEEP(mx1, gb1, sec1, i21, t31, 1)
        MERGE_KEEP(mx2, gb2, sec2, i22, t32, 2)
        MERGE_KEEP(mx3, gb3, sec3, i23, t33, 3)
#undef MERGE_KEEP

        // ---- certified resolution ----
        int bi;
        if (kmx - kt3 <= EPS2) {
            // full exact no-FMA argmax (rare)
            float bb2 = -INFINITY;
            int bj = 0;
            for (int p = 0; p < NB / 2; ++p) {
                const v2f* wr = &WP[p * H];
                float a0 = 0.0f, a1 = 0.0f;
#pragma unroll
                for (int k = 0; k < H; ++k) {
                    v2f w = wr[k];
                    a0 = a0 + h[k] * w.x;
                    a1 = a1 + h[k] * w.y;
                }
                a0 = a0 + b_out[2 * p];
                a1 = a1 + b_out[2 * p + 1];
                if (a0 > bb2) { bb2 = a0; bj = 2 * p; }
                if (a1 > bb2) { bb2 = a1; bj = 2 * p + 1; }
            }
            bi = bj;
        } else if (kmx - ksec <= EPS2) {
            // exact 2-bin duel, first-index ties
            int lo  = kgb < ki2 ? kgb : ki2;
            int hi2 = kgb < ki2 ? ki2 : kgb;
            float El = 0.0f, Eh = 0.0f;
            {
                const float* wr = ws + (lo >> 1) * 32 + (lo & 1);
#pragma unroll
                for (int k = 0; k < H; ++k) El = El + h[k] * wr[2 * k];
                El = El + b_out[lo];
            }
            {
                const float* wr = ws + (hi2 >> 1) * 32 + (hi2 & 1);
#pragma unroll
                for (int k = 0; k < H; ++k) Eh = Eh + h[k] * wr[2 * k];
                Eh = Eh + b_out[hi2];
            }
            bi = (Eh > El) ? hi2 : lo;
        } else {
            bi = kgb;
        }
        o[d] = bi;

        // ---- h = h + embed[bi] : EXACT (global gather, cached) ----
        {
            const float4* e = reinterpret_cast<const float4*>(embed + bi * H);
#pragma unroll
            for (int q4 = 0; q4 < 4; ++q4) {
                float4 ev = e[q4];
                h[q4 * 4 + 0] = h[q4 * 4 + 0] + ev.x;
                h[q4 * 4 + 1] = h[q4 * 4 + 1] + ev.y;
                h[q4 * 4 + 2] = h[q4 * 4 + 2] + ev.z;
                h[q4 * 4 + 3] = h[q4 * 4 + 3] + ev.w;
            }
        }

        // ---- z = h @ W_mlp + b_mlp ; silu : EXACT no-FMA + np-exp ----
        float hn[H];
#pragma unroll
        for (int i = 0; i < H; ++i) {
            const float* wr = &WM[i * H];
            float acc = 0.0f;
#pragma unroll
            for (int k = 0; k < H; ++k) acc = acc + h[k] * wr[k];
            acc = acc + b_mlp[i];
            float e = np_expf(-acc);
            float s = 1.0f / (1.0f + e);
            hn[i] = acc * s;
        }
#pragma unroll
        for (int i = 0; i < H; ++i) h[i] = hn[i];
    }
}

extern "C" void kernel_launch(void* const* d_in, const int* in_sizes, int n_in,
                              void* d_out, int out_size, void* d_ws, size_t ws_size,
                              hipStream_t stream) {
    const float* x     = (const float*)d_in[0];
    const float* W_in  = (const float*)d_in[1];
    const float* b_in  = (const float*)d_in[2];
    const float* embed = (const float*)d_in[3];
    const float* W_mlp = (const float*)d_in[4];
    const float* b_mlp = (const float*)d_in[5];
    const float* W_out = (const float*)d_in[6];
    const float* b_out = (const float*)d_in[7];
    int* out  = (int*)d_out;
    float* ws = (float*)d_ws;          // needs (4096+256)*4 = 17.4 KB

    addrnet_prep_kernel<<<1, 256, 0, stream>>>(W_out, W_mlp, ws);

    dim3 grid(BATCH / BLOCK);          // 2048 blocks, 8192 waves
    dim3 block(BLOCK);
    addrnet_r18_kernel<<<grid, block, 0, stream>>>(x, W_in, b_in, embed,
                                                   b_mlp, b_out, W_out, ws, out);
}